// Round 8
// baseline (204.581 us; speedup 1.0000x reference)
//
#include <hip/hip_runtime.h>
#include <hip/hip_fp16.h>

#define N_NODES 100000
#define E_EDGES 1600000
#define IN_C 128
#define HID_C 64
#define OUT_C 32
#define BNODES 256                                  // nodes per bucket (dst>>8)
#define NBUCK ((N_NODES + BNODES - 1) / BNODES)     // 391
#define MAXB 4608                                   // bucket cap (mean 4092, sd~64 -> +8 sigma)
#define NCHUNK 256                                  // edge chunks (privatized sort)
#define CHUNK_E (E_EDGES / NCHUNK)                  // 6250
#define SCAN_N (NBUCK * NCHUNK)                     // 100096 counts
#define SCAN_NB (SCAN_N / 256)                      // 391 blocks (bsums[i] pairs with hist row i)
#define NT 8                                        // src tiles (12.8MB hs / 8 = 1.6MB/tile)
#define TILE_DIV 12500                              // src / 12500 -> tile 0..7

// v_fma_mix_f32: acc(f32) += cvt_f32(f16 half of u) * wt(f32). One VALU per channel-value
// (vs cvt+add = 2), fp32 accumulation preserved exactly.
#define FMX_LO(acc, u, wt) asm("v_fma_mix_f32 %0, %1, %2, %0 op_sel:[0,0,0] op_sel_hi:[1,0,0]" \
                               : "+v"(acc) : "v"(u), "v"(wt))
#define FMX_HI(acc, u, wt) asm("v_fma_mix_f32 %0, %1, %2, %0 op_sel:[1,0,0] op_sel_hi:[1,0,0]" \
                               : "+v"(acc) : "v"(u), "v"(wt))

// NOTE: macro param must NOT be named 'w'/'x'/'y'/'z' — it would substitute into the
// vector member access (v).w (round-2 compile failure).
#define ACC8(v, wt) do { \
        FMX_LO(a0, (v).x, wt); FMX_HI(a1, (v).x, wt); \
        FMX_LO(a2, (v).y, wt); FMX_HI(a3, (v).y, wt); \
        FMX_LO(a4, (v).z, wt); FMX_HI(a5, (v).z, wt); \
        FMX_LO(a6, (v).w, wt); FMX_HI(a7, (v).w, wt); } while (0)

#define ACC4(v, wt) do { \
        FMX_LO(a0, (v).x, wt); FMX_HI(a1, (v).x, wt); \
        FMX_LO(a2, (v).y, wt); FMX_HI(a3, (v).y, wt); } while (0)

// chunk<->block swizzle: consecutive chunks land on the same XCD (blockIdx%8 heuristic),
// so adjacent pairs-windows (shared 64B lines) merge in one L2 instead of ping-ponging.
__device__ __forceinline__ int chunk_of_block(int b) { return (b & 7) * (NCHUNK / 8) + (b >> 3); }

// ---- chunk histogram: block k histograms its 6250-edge slice in LDS (1024 thr) ----
__global__ __launch_bounds__(1024) void chunk_hist_kernel(const int* __restrict__ dst,
                                                          int* __restrict__ hist) {
    __shared__ int h[NBUCK];
    for (int i = threadIdx.x; i < NBUCK; i += 1024) h[i] = 0;
    __syncthreads();
    const int chunk = chunk_of_block(blockIdx.x);
    const int base = chunk * CHUNK_E;
    for (int j = threadIdx.x; j < CHUNK_E; j += 1024)
        atomicAdd(&h[dst[base + j] >> 8], 1);
    __syncthreads();
    for (int i = threadIdx.x; i < NBUCK; i += 1024)
        hist[i * NCHUNK + chunk] = h[i];
}

// ---- scan stage 1 (the ONLY scan kernel now): per-bucket-row exclusive scan;
//      bsums[b] = bucket b's TOTAL edge count (consumers compute the 391-prefix
//      themselves in LDS — the old scan2 launch is folded away). ----
__global__ void scan1_kernel(int* __restrict__ data, int* __restrict__ bsums) {
    __shared__ int s[256];
    int i = blockIdx.x * 256 + threadIdx.x;
    int v = data[i];
    s[threadIdx.x] = v;
    __syncthreads();
    for (int off = 1; off < 256; off <<= 1) {
        int t = (threadIdx.x >= off) ? s[threadIdx.x - off] : 0;
        __syncthreads();
        s[threadIdx.x] += t;
        __syncthreads();
    }
    data[i] = s[threadIdx.x] - v;                   // exclusive within bucket row
    if (threadIdx.x == 255) bsums[blockIdx.x] = s[255];
}

// ---- chunk fill: block k scatters its slice into PRIVATE windows.
//      Computes the 391-bucket exclusive prefix in LDS (9 Hillis-Steele steps on
//      1024 threads) instead of a separate scan2 launch.
//      Global offset of (bucket i, chunk) = hist[i*256+chunk] + prefix(i). ----
__global__ __launch_bounds__(1024) void chunk_fill_kernel(const int* __restrict__ src,
                                                          const int* __restrict__ dst,
                                                          const int* __restrict__ hist,
                                                          const int* __restrict__ bsums,
                                                          unsigned* __restrict__ pairs) {
    __shared__ int sb[NBUCK];                       // bucket totals -> inclusive scan
    __shared__ int cur[NBUCK];
    const int tid = threadIdx.x;
    int v = (tid < NBUCK) ? bsums[tid] : 0;
    if (tid < NBUCK) sb[tid] = v;
    __syncthreads();
    for (int off = 1; off < NBUCK; off <<= 1) {
        int t = (tid >= off && tid < NBUCK) ? sb[tid - off] : 0;
        __syncthreads();
        if (tid < NBUCK) sb[tid] += t;
        __syncthreads();
    }
    const int chunk = chunk_of_block(blockIdx.x);
    if (tid < NBUCK)
        cur[tid] = hist[tid * NCHUNK + chunk] + (sb[tid] - v);   // exclusive prefix
    __syncthreads();
    const int base = chunk * CHUNK_E;
    for (int j = tid; j < CHUNK_E; j += 1024) {
        int d = dst[base + j];
        int pos = atomicAdd(&cur[d >> 8], 1);
        pairs[pos] = ((unsigned)src[base + j] << 8) | (unsigned)(d & 255);
    }
}

// ---- per-bucket counting sort -> node-level CSR, in place (LDS stage).
//      beg = prefix(b) via a 2-iteration reduction (only this bucket's prefix needed).
//      Sort key = (node, src/12500): neighbor lists come out src-tile-ordered. ----
__global__ __launch_bounds__(256) void bucket_sort_kernel(const int* __restrict__ bsums,
                                                          unsigned* __restrict__ pairs,
                                                          int* __restrict__ row_ptr,
                                                          float* __restrict__ dinv) {
    __shared__ unsigned sp[MAXB];
    __shared__ unsigned so[MAXB];
    __shared__ int cur[BNODES * NT];                // 2048 counters (node x tile)
    __shared__ int s256[BNODES];
    const int b = blockIdx.x;
    const int tid = threadIdx.x;
    // ---- beg = sum of bucket totals [0..b) ----
    int part = 0;
    for (int i = tid; i < b; i += 256) part += bsums[i];
    s256[tid] = part;
    __syncthreads();
    for (int off = 128; off > 0; off >>= 1) {
        if (tid < off) s256[tid] += s256[tid + off];
        __syncthreads();
    }
    const int beg = s256[0];
    const int cnt = bsums[b];
    __syncthreads();
#pragma unroll
    for (int q = 0; q < NT; ++q) cur[tid * NT + q] = 0;
    __syncthreads();
    for (int j = tid; j < cnt; j += 256) {
        unsigned p = pairs[beg + j];
        sp[j] = p;
        atomicAdd(&cur[(p & 255) * NT + (p >> 8) / TILE_DIV], 1);
    }
    __syncthreads();
    int a[NT];
    int lsum = 0;
#pragma unroll
    for (int q = 0; q < NT; ++q) { a[q] = cur[tid * NT + q]; lsum += a[q]; }
    s256[tid] = lsum;
    __syncthreads();
    for (int off = 1; off < 256; off <<= 1) {       // inclusive scan over node totals
        int t = (tid >= off) ? s256[tid - off] : 0;
        __syncthreads();
        s256[tid] += t;
        __syncthreads();
    }
    int run = s256[tid] - lsum;                     // exclusive prefix for this node
    int node = b * BNODES + tid;
    if (node < N_NODES) {
        row_ptr[node] = beg + run;
        dinv[node] = rsqrtf((float)lsum + 1.0f);
    }
    if (tid == 0 && b == NBUCK - 1) row_ptr[N_NODES] = E_EDGES;
#pragma unroll
    for (int q = 0; q < NT; ++q) { cur[tid * NT + q] = run; run += a[q]; }
    __syncthreads();
    for (int j = tid; j < cnt; j += 256) {
        unsigned p = sp[j];
        int pos = atomicAdd(&cur[(p & 255) * NT + (p >> 8) / TILE_DIV], 1);
        so[pos] = p >> 8;                           // scatter stays in LDS
    }
    __syncthreads();
    for (int j = tid; j < cnt; j += 256)
        pairs[beg + j] = so[j];                     // coalesced writeback
}

// ---- hs(fp16) = dinv[row] * (x @ W1) : 4 rows x 8 cols per thread, 128 rows/block ----
__global__ __launch_bounds__(256) void gemm1_kernel(const float* __restrict__ x,
                                                    const float* __restrict__ W1,
                                                    const float* __restrict__ dinv,
                                                    __half* __restrict__ hs) {
    __shared__ float sW[IN_C * HID_C];
    for (int i = threadIdx.x; i < IN_C * HID_C; i += 256) sW[i] = W1[i];
    __syncthreads();
    const int cg = (threadIdx.x & 7) * 8;
    const int row0 = blockIdx.x * 128 + (threadIdx.x >> 3) * 4;
    float acc[4][8];
#pragma unroll
    for (int r = 0; r < 4; ++r)
#pragma unroll
        for (int c = 0; c < 8; ++c) acc[r][c] = 0.f;

    int rr[4];
#pragma unroll
    for (int r = 0; r < 4; ++r) rr[r] = min(row0 + r, N_NODES - 1);

    const float4* x4 = (const float4*)x;
#pragma unroll 2
    for (int k4 = 0; k4 < IN_C / 4; ++k4) {
        float4 xv[4];
#pragma unroll
        for (int r = 0; r < 4; ++r) xv[r] = x4[(size_t)rr[r] * (IN_C / 4) + k4];
        float xs[4][4];
#pragma unroll
        for (int r = 0; r < 4; ++r) {
            xs[r][0] = xv[r].x; xs[r][1] = xv[r].y; xs[r][2] = xv[r].z; xs[r][3] = xv[r].w;
        }
#pragma unroll
        for (int kk = 0; kk < 4; ++kk) {
            const float4* wp = (const float4*)(sW + (k4 * 4 + kk) * HID_C + cg);
            float4 w0 = wp[0], w1 = wp[1];
            float wv[8] = {w0.x, w0.y, w0.z, w0.w, w1.x, w1.y, w1.z, w1.w};
#pragma unroll
            for (int r = 0; r < 4; ++r)
#pragma unroll
                for (int c = 0; c < 8; ++c)
                    acc[r][c] = fmaf(xs[r][kk], wv[c], acc[r][c]);
        }
    }
#pragma unroll
    for (int r = 0; r < 4; ++r) {
        int row = row0 + r;
        if (row < N_NODES) {
            float dv = dinv[row];
            union { float4 f; __half2 h[4]; } u;
#pragma unroll
            for (int q = 0; q < 4; ++q)
                u.h[q] = __floats2half2_rn(acc[r][2 * q] * dv, acc[r][2 * q + 1] * dv);
            *(float4*)(hs + (size_t)row * HID_C + cg) = u.f;   // 16 B packed store
        }
    }
}

// ---- layer-1 aggregate FUSED with gemm2. 8 nodes/wave, 8 lanes/node, uint4 (16B =
//      8 fp16 channels) per lane. Tail is now TWO 4-deep predicated halves: the
//      second half is branch-skipped when r<=4, halving wasted clamped gathers
//      (~26 MB of overfetch in the old single 8-deep tail). ----
__global__ __launch_bounds__(256) void agg1_gemm2_kernel(const int* __restrict__ row_ptr,
                                                         const int* __restrict__ col,
                                                         const __half* __restrict__ hs,
                                                         const float* __restrict__ dinv,
                                                         const float* __restrict__ b1,
                                                         const float* __restrict__ W2,
                                                         __half* __restrict__ gs) {
    __shared__ float sW[HID_C * OUT_C];                 // 8 KB, [k][c] row-major
    __shared__ float sh[32 * 68];                       // 32 nodes x 64ch, stride 68 (bank-spread)
    for (int i = threadIdx.x; i < HID_C * OUT_C; i += 256) sW[i] = W2[i];
    const int ln = threadIdx.x >> 3;                    // node slot 0..31
    const int cl = threadIdx.x & 7;                     // lane in node: channels 8cl..8cl+7
    const int node = blockIdx.x * 32 + ln;              // grid 3125 exact
    const int beg = row_ptr[node], end = row_ptr[node + 1];
    const char* hsb = (const char*)hs;
    const int lo = cl * 16;                             // byte offset within 128-B row
    float one = 1.0f;
    float a0 = 0.f, a1 = 0.f, a2 = 0.f, a3 = 0.f, a4 = 0.f, a5 = 0.f, a6 = 0.f, a7 = 0.f;
    {
        uint4 sv = *(const uint4*)(hsb + node * 128 + lo);   // self loop
        ACC8(sv, one);
    }
    int j = beg;
    for (; j + 8 <= end; j += 8) {                      // 8 independent gathers in flight
        int i0 = col[j],     i1 = col[j + 1], i2 = col[j + 2], i3 = col[j + 3];
        int i4 = col[j + 4], i5 = col[j + 5], i6 = col[j + 6], i7 = col[j + 7];
        uint4 v0 = *(const uint4*)(hsb + i0 * 128 + lo);
        uint4 v1 = *(const uint4*)(hsb + i1 * 128 + lo);
        uint4 v2 = *(const uint4*)(hsb + i2 * 128 + lo);
        uint4 v3 = *(const uint4*)(hsb + i3 * 128 + lo);
        uint4 v4 = *(const uint4*)(hsb + i4 * 128 + lo);
        uint4 v5 = *(const uint4*)(hsb + i5 * 128 + lo);
        uint4 v6 = *(const uint4*)(hsb + i6 * 128 + lo);
        uint4 v7 = *(const uint4*)(hsb + i7 * 128 + lo);
        ACC8(v0, one); ACC8(v1, one); ACC8(v2, one); ACC8(v3, one);
        ACC8(v4, one); ACC8(v5, one); ACC8(v6, one); ACC8(v7, one);
    }
    if (j < end) {                                      // predicated tail, 2 x 4-deep
        const int e1 = end - 1;
#pragma unroll
        for (int k = 0; k < 4; ++k) {
            int jj = j + k;
            int s = col[min(jj, e1)];
            float wt = (jj < end) ? 1.0f : 0.0f;
            uint4 v = *(const uint4*)(hsb + s * 128 + lo);
            ACC8(v, wt);
        }
        if (j + 4 < end) {                              // skipped when r<=4
#pragma unroll
            for (int k = 4; k < 8; ++k) {
                int jj = j + k;
                int s = col[min(jj, e1)];
                float wt = (jj < end) ? 1.0f : 0.0f;
                uint4 v = *(const uint4*)(hsb + s * 128 + lo);
                ACC8(v, wt);
            }
        }
    }
    const float dv = dinv[node];
    const float4* b4 = (const float4*)b1;
    float4 bb0 = b4[2 * cl], bb1 = b4[2 * cl + 1];
    float4 h0, h1;
    h0.x = fmaxf(fmaf(dv, a0, bb0.x), 0.f);
    h0.y = fmaxf(fmaf(dv, a1, bb0.y), 0.f);
    h0.z = fmaxf(fmaf(dv, a2, bb0.z), 0.f);
    h0.w = fmaxf(fmaf(dv, a3, bb0.w), 0.f);
    h1.x = fmaxf(fmaf(dv, a4, bb1.x), 0.f);
    h1.y = fmaxf(fmaf(dv, a5, bb1.y), 0.f);
    h1.z = fmaxf(fmaf(dv, a6, bb1.z), 0.f);
    h1.w = fmaxf(fmaf(dv, a7, bb1.w), 0.f);
    *(float4*)&sh[ln * 68 + 8 * cl] = h0;               // h2 row, fp32 in LDS
    *(float4*)&sh[ln * 68 + 8 * cl + 4] = h1;
    __syncthreads();                                    // also covers sW load
    // gs[node][oc..oc+3] = dv * sum_k h2[k] * W2[k][oc..oc+3]
    float g0 = 0.f, g1 = 0.f, g2 = 0.f, g3 = 0.f;
    const int oc = 4 * cl;
#pragma unroll
    for (int k4 = 0; k4 < HID_C / 4; ++k4) {
        float4 hv = *(const float4*)&sh[ln * 68 + 4 * k4];   // bank 4(ln+k4)%32: conflict-free
#pragma unroll
        for (int q = 0; q < 4; ++q) {
            float hq = (q == 0) ? hv.x : (q == 1) ? hv.y : (q == 2) ? hv.z : hv.w;
            float4 wv = *(const float4*)&sW[(4 * k4 + q) * OUT_C + oc];
            g0 = fmaf(hq, wv.x, g0);
            g1 = fmaf(hq, wv.y, g1);
            g2 = fmaf(hq, wv.z, g2);
            g3 = fmaf(hq, wv.w, g3);
        }
    }
    union { uint2 u; __half2 h[2]; } go;
    go.h[0] = __floats2half2_rn(g0 * dv, g1 * dv);
    go.h[1] = __floats2half2_rn(g2 * dv, g3 * dv);
    *(uint2*)(gs + (size_t)node * OUT_C + oc) = go.u;   // 8 B x 8 lanes = 64 B/node
}

// ---- layer-2 aggregate: 8 nodes/wave, 8 lanes/node, uint2 (8B = 4 fp16 ch) per lane.
//      Same 2 x 4-deep predicated tail (halves clamped-gather overfetch). ----
__global__ __launch_bounds__(256) void agg2_kernel(const int* __restrict__ row_ptr,
                                                   const int* __restrict__ col,
                                                   const __half* __restrict__ gsr,
                                                   const float* __restrict__ dinv,
                                                   const float* __restrict__ b2,
                                                   float* __restrict__ out) {
    const int ln = threadIdx.x >> 3;                    // node slot 0..31
    const int cl = threadIdx.x & 7;                     // channels 4cl..4cl+3
    const int node = blockIdx.x * 32 + ln;              // grid 3125 exact
    const int beg = row_ptr[node], end = row_ptr[node + 1];
    const char* gb = (const char*)gsr;
    const int lo = cl * 8;                              // byte offset within 64-B row
    float one = 1.0f;
    float a0 = 0.f, a1 = 0.f, a2 = 0.f, a3 = 0.f;
    {
        uint2 sv = *(const uint2*)(gb + node * 64 + lo);     // self loop
        ACC4(sv, one);
    }
    int j = beg;
    for (; j + 8 <= end; j += 8) {
        int i0 = col[j],     i1 = col[j + 1], i2 = col[j + 2], i3 = col[j + 3];
        int i4 = col[j + 4], i5 = col[j + 5], i6 = col[j + 6], i7 = col[j + 7];
        uint2 v0 = *(const uint2*)(gb + i0 * 64 + lo);
        uint2 v1 = *(const uint2*)(gb + i1 * 64 + lo);
        uint2 v2 = *(const uint2*)(gb + i2 * 64 + lo);
        uint2 v3 = *(const uint2*)(gb + i3 * 64 + lo);
        uint2 v4 = *(const uint2*)(gb + i4 * 64 + lo);
        uint2 v5 = *(const uint2*)(gb + i5 * 64 + lo);
        uint2 v6 = *(const uint2*)(gb + i6 * 64 + lo);
        uint2 v7 = *(const uint2*)(gb + i7 * 64 + lo);
        ACC4(v0, one); ACC4(v1, one); ACC4(v2, one); ACC4(v3, one);
        ACC4(v4, one); ACC4(v5, one); ACC4(v6, one); ACC4(v7, one);
    }
    if (j < end) {                                      // predicated tail, 2 x 4-deep
        const int e1 = end - 1;
#pragma unroll
        for (int k = 0; k < 4; ++k) {
            int jj = j + k;
            int s = col[min(jj, e1)];
            float wt = (jj < end) ? 1.0f : 0.0f;
            uint2 v = *(const uint2*)(gb + s * 64 + lo);
            ACC4(v, wt);
        }
        if (j + 4 < end) {                              // skipped when r<=4
#pragma unroll
            for (int k = 4; k < 8; ++k) {
                int jj = j + k;
                int s = col[min(jj, e1)];
                float wt = (jj < end) ? 1.0f : 0.0f;
                uint2 v = *(const uint2*)(gb + s * 64 + lo);
                ACC4(v, wt);
            }
        }
    }
    const float dv = dinv[node];
    float4 bb = ((const float4*)b2)[cl];
    float4 o;
    o.x = fmaf(dv, a0, bb.x);
    o.y = fmaf(dv, a1, bb.y);
    o.z = fmaf(dv, a2, bb.z);
    o.w = fmaf(dv, a3, bb.w);
    *(float4*)(out + (size_t)node * OUT_C + 4 * cl) = o;   // 16 B x 8 lanes = 128 B/node
}

extern "C" void kernel_launch(void* const* d_in, const int* in_sizes, int n_in,
                              void* d_out, int out_size, void* d_ws, size_t ws_size,
                              hipStream_t stream) {
    const float* x  = (const float*)d_in[0];   // [N,128]
    const int*   ei = (const int*)d_in[1];     // [2,E]
    const float* W1 = (const float*)d_in[2];   // [128,64]
    const float* b1 = (const float*)d_in[3];   // [64]
    const float* W2 = (const float*)d_in[4];   // [64,32]
    const float* b2 = (const float*)d_in[5];   // [32]
    float* out = (float*)d_out;                // [N,32]

    const int* srcv = ei;
    const int* dstv = ei + E_EDGES;

    // workspace layout (~33 MB)
    float* dinv  = (float*)d_ws;                           // N floats
    __half* hs   = (__half*)(dinv + N_NODES);              // N*64 halves (layer-1 features)
    __half* gs   = hs + (size_t)N_NODES * HID_C;           // N*32 halves (fused agg1+gemm2 out;
                                                           //  must NOT alias hs — read concurrently)
    int* hist      = (int*)(gs + (size_t)N_NODES * HID_C); // NBUCK*NCHUNK (100k)
    int* bsums     = hist + SCAN_N;                        // NBUCK bucket TOTALS (not scanned)
    int* row_ptr   = bsums + SCAN_NB;                      // N+1
    unsigned* pairs = (unsigned*)(row_ptr + N_NODES + 1);  // E (pairs -> sorted src = col)
    int* col = (int*)pairs;

    // CSR build: chunk-privatized counting sort (scan2 folded into consumers; 4 kernels)
    chunk_hist_kernel<<<NCHUNK, 1024, 0, stream>>>(dstv, hist);
    scan1_kernel<<<SCAN_NB, 256, 0, stream>>>(hist, bsums);
    chunk_fill_kernel<<<NCHUNK, 1024, 0, stream>>>(srcv, dstv, hist, bsums, pairs);
    bucket_sort_kernel<<<NBUCK, 256, 0, stream>>>(bsums, pairs, row_ptr, dinv);

    // layer 1 (+ fused layer-2 GEMM)
    gemm1_kernel<<<(N_NODES + 127) / 128, 256, 0, stream>>>(x, W1, dinv, hs);
    agg1_gemm2_kernel<<<N_NODES / 32, 256, 0, stream>>>(row_ptr, col, hs, dinv, b1, W2, gs);

    // layer 2 aggregate
    agg2_kernel<<<N_NODES / 32, 256, 0, stream>>>(row_ptr, col, gs, dinv, b2, out);
}

// Round 9
// 200.290 us; speedup vs baseline: 1.0214x; 1.0214x over previous
//
#include <hip/hip_runtime.h>
#include <hip/hip_fp16.h>

#define N_NODES 100000
#define E_EDGES 1600000
#define IN_C 128
#define HID_C 64
#define OUT_C 32
#define BNODES 256                                  // nodes per bucket (dst>>8)
#define NBUCK ((N_NODES + BNODES - 1) / BNODES)     // 391
#define MAXB 4608                                   // bucket cap (mean 4092, sd~64 -> +8 sigma)
#define NCHUNK 256                                  // edge chunks (privatized sort)
#define CHUNK_E (E_EDGES / NCHUNK)                  // 6250
#define SCAN_N (NBUCK * NCHUNK)                     // 100096 counts
#define SCAN_NB (SCAN_N / 256)                      // 391 blocks (bsums[i] pairs with hist row i)
#define NT 8                                        // src tiles (12.8MB hs / 8 = 1.6MB/tile)
#define TILE_DIV 12500                              // src / 12500 -> tile 0..7

// v_fma_mix_f32: acc(f32) += cvt_f32(f16 half of u) * wt(f32). One VALU per channel-value
// (vs cvt+add = 2), fp32 accumulation preserved exactly.
#define FMX_LO(acc, u, wt) asm("v_fma_mix_f32 %0, %1, %2, %0 op_sel:[0,0,0] op_sel_hi:[1,0,0]" \
                               : "+v"(acc) : "v"(u), "v"(wt))
#define FMX_HI(acc, u, wt) asm("v_fma_mix_f32 %0, %1, %2, %0 op_sel:[1,0,0] op_sel_hi:[1,0,0]" \
                               : "+v"(acc) : "v"(u), "v"(wt))

// NOTE: macro param must NOT be named 'w'/'x'/'y'/'z' — it would substitute into the
// vector member access (v).w (round-2 compile failure).
#define ACC8(v, wt) do { \
        FMX_LO(a0, (v).x, wt); FMX_HI(a1, (v).x, wt); \
        FMX_LO(a2, (v).y, wt); FMX_HI(a3, (v).y, wt); \
        FMX_LO(a4, (v).z, wt); FMX_HI(a5, (v).z, wt); \
        FMX_LO(a6, (v).w, wt); FMX_HI(a7, (v).w, wt); } while (0)

// chunk<->block swizzle: consecutive chunks land on the same XCD (blockIdx%8 heuristic),
// so adjacent pairs-windows (shared 64B lines) merge in one L2 instead of ping-ponging.
__device__ __forceinline__ int chunk_of_block(int b) { return (b & 7) * (NCHUNK / 8) + (b >> 3); }

// ---- chunk histogram: block k histograms its 6250-edge slice in LDS (1024 thr) ----
__global__ __launch_bounds__(1024) void chunk_hist_kernel(const int* __restrict__ dst,
                                                          int* __restrict__ hist) {
    __shared__ int h[NBUCK];
    for (int i = threadIdx.x; i < NBUCK; i += 1024) h[i] = 0;
    __syncthreads();
    const int chunk = chunk_of_block(blockIdx.x);
    const int base = chunk * CHUNK_E;
    for (int j = threadIdx.x; j < CHUNK_E; j += 1024)
        atomicAdd(&h[dst[base + j] >> 8], 1);
    __syncthreads();
    for (int i = threadIdx.x; i < NBUCK; i += 1024)
        hist[i * NCHUNK + chunk] = h[i];
}

// ---- scan stage 1: per-256-block (= per-bucket-row) exclusive scan; row totals out ----
__global__ void scan1_kernel(int* __restrict__ data, int* __restrict__ bsums) {
    __shared__ int s[256];
    int i = blockIdx.x * 256 + threadIdx.x;
    int v = data[i];
    s[threadIdx.x] = v;
    __syncthreads();
    for (int off = 1; off < 256; off <<= 1) {
        int t = (threadIdx.x >= off) ? s[threadIdx.x - off] : 0;
        __syncthreads();
        s[threadIdx.x] += t;
        __syncthreads();
    }
    data[i] = s[threadIdx.x] - v;                   // exclusive within bucket row
    if (threadIdx.x == 255) bsums[blockIdx.x] = s[255];
}

// ---- scan stage 2: exclusive scan of the 391 block sums (single block, 1 pass) ----
__global__ __launch_bounds__(1024) void scan2_kernel(int* __restrict__ bsums) {
    __shared__ int s[1024];
    int i = threadIdx.x;
    int v = (i < SCAN_NB) ? bsums[i] : 0;
    s[i] = v;
    __syncthreads();
    for (int off = 1; off < 1024; off <<= 1) {
        int t = (i >= off) ? s[i - off] : 0;
        __syncthreads();
        s[i] += t;
        __syncthreads();
    }
    if (i < SCAN_NB) bsums[i] = s[i] - v;
}

// ---- chunk fill: block k scatters its slice into PRIVATE windows.
//      Global offset of (bucket i, chunk) = hist[i*256+chunk] + bsums[i]. ----
__global__ __launch_bounds__(1024) void chunk_fill_kernel(const int* __restrict__ src,
                                                          const int* __restrict__ dst,
                                                          const int* __restrict__ hist,
                                                          const int* __restrict__ bsums,
                                                          unsigned* __restrict__ pairs) {
    __shared__ int cur[NBUCK];
    const int chunk = chunk_of_block(blockIdx.x);
    for (int i = threadIdx.x; i < NBUCK; i += 1024)
        cur[i] = hist[i * NCHUNK + chunk] + bsums[i];
    __syncthreads();
    const int base = chunk * CHUNK_E;
    for (int j = threadIdx.x; j < CHUNK_E; j += 1024) {
        int d = dst[base + j];
        int pos = atomicAdd(&cur[d >> 8], 1);
        pairs[pos] = ((unsigned)src[base + j] << 8) | (unsigned)(d & 255);
    }
}

// ---- per-bucket counting sort -> node-level CSR, in place (LDS stage).
//      Sort key = (node, src/12500): neighbor lists come out src-tile-ordered. ----
__global__ __launch_bounds__(256) void bucket_sort_kernel(const int* __restrict__ bsums,
                                                          unsigned* __restrict__ pairs,
                                                          int* __restrict__ row_ptr,
                                                          float* __restrict__ dinv) {
    __shared__ unsigned sp[MAXB];
    __shared__ unsigned so[MAXB];
    __shared__ int cur[BNODES * NT];                // 2048 counters (node x tile)
    __shared__ int s256[BNODES];
    const int b = blockIdx.x;
    const int tid = threadIdx.x;
    const int beg = bsums[b];
    const int end = (b + 1 < NBUCK) ? bsums[b + 1] : E_EDGES;
    const int cnt = end - beg;
#pragma unroll
    for (int q = 0; q < NT; ++q) cur[tid * NT + q] = 0;
    __syncthreads();
    for (int j = tid; j < cnt; j += 256) {
        unsigned p = pairs[beg + j];
        sp[j] = p;
        atomicAdd(&cur[(p & 255) * NT + (p >> 8) / TILE_DIV], 1);
    }
    __syncthreads();
    int a[NT];
    int lsum = 0;
#pragma unroll
    for (int q = 0; q < NT; ++q) { a[q] = cur[tid * NT + q]; lsum += a[q]; }
    s256[tid] = lsum;
    __syncthreads();
    for (int off = 1; off < 256; off <<= 1) {       // inclusive scan over node totals
        int t = (tid >= off) ? s256[tid - off] : 0;
        __syncthreads();
        s256[tid] += t;
        __syncthreads();
    }
    int run = s256[tid] - lsum;                     // exclusive prefix for this node
    int node = b * BNODES + tid;
    if (node < N_NODES) {
        row_ptr[node] = beg + run;
        dinv[node] = rsqrtf((float)lsum + 1.0f);
    }
    if (tid == 0 && b == NBUCK - 1) row_ptr[N_NODES] = E_EDGES;
#pragma unroll
    for (int q = 0; q < NT; ++q) { cur[tid * NT + q] = run; run += a[q]; }
    __syncthreads();
    for (int j = tid; j < cnt; j += 256) {
        unsigned p = sp[j];
        int pos = atomicAdd(&cur[(p & 255) * NT + (p >> 8) / TILE_DIV], 1);
        so[pos] = p >> 8;                           // scatter stays in LDS
    }
    __syncthreads();
    for (int j = tid; j < cnt; j += 256)
        pairs[beg + j] = so[j];                     // coalesced writeback
}

// ---- hs(fp16) = dinv[row] * (x @ W1) : 4 rows x 8 cols per thread, 128 rows/block ----
__global__ __launch_bounds__(256) void gemm1_kernel(const float* __restrict__ x,
                                                    const float* __restrict__ W1,
                                                    const float* __restrict__ dinv,
                                                    __half* __restrict__ hs) {
    __shared__ float sW[IN_C * HID_C];
    for (int i = threadIdx.x; i < IN_C * HID_C; i += 256) sW[i] = W1[i];
    __syncthreads();
    const int cg = (threadIdx.x & 7) * 8;
    const int row0 = blockIdx.x * 128 + (threadIdx.x >> 3) * 4;
    float acc[4][8];
#pragma unroll
    for (int r = 0; r < 4; ++r)
#pragma unroll
        for (int c = 0; c < 8; ++c) acc[r][c] = 0.f;

    int rr[4];
#pragma unroll
    for (int r = 0; r < 4; ++r) rr[r] = min(row0 + r, N_NODES - 1);

    const float4* x4 = (const float4*)x;
#pragma unroll 2
    for (int k4 = 0; k4 < IN_C / 4; ++k4) {
        float4 xv[4];
#pragma unroll
        for (int r = 0; r < 4; ++r) xv[r] = x4[(size_t)rr[r] * (IN_C / 4) + k4];
        float xs[4][4];
#pragma unroll
        for (int r = 0; r < 4; ++r) {
            xs[r][0] = xv[r].x; xs[r][1] = xv[r].y; xs[r][2] = xv[r].z; xs[r][3] = xv[r].w;
        }
#pragma unroll
        for (int kk = 0; kk < 4; ++kk) {
            const float4* wp = (const float4*)(sW + (k4 * 4 + kk) * HID_C + cg);
            float4 w0 = wp[0], w1 = wp[1];
            float wv[8] = {w0.x, w0.y, w0.z, w0.w, w1.x, w1.y, w1.z, w1.w};
#pragma unroll
            for (int r = 0; r < 4; ++r)
#pragma unroll
                for (int c = 0; c < 8; ++c)
                    acc[r][c] = fmaf(xs[r][kk], wv[c], acc[r][c]);
        }
    }
#pragma unroll
    for (int r = 0; r < 4; ++r) {
        int row = row0 + r;
        if (row < N_NODES) {
            float dv = dinv[row];
            union { float4 f; __half2 h[4]; } u;
#pragma unroll
            for (int q = 0; q < 4; ++q)
                u.h[q] = __floats2half2_rn(acc[r][2 * q] * dv, acc[r][2 * q + 1] * dv);
            *(float4*)(hs + (size_t)row * HID_C + cg) = u.f;   // 16 B packed store
        }
    }
}

// ---- layer-1 aggregate FUSED with gemm2. 8 nodes/wave, 8 lanes/node, uint4 (16B =
//      8 fp16 channels) per lane. One gather instruction = 8 edges x 128B rows = 1KB.
//      (round-7 proven form) ----
__global__ __launch_bounds__(256) void agg1_gemm2_kernel(const int* __restrict__ row_ptr,
                                                         const int* __restrict__ col,
                                                         const __half* __restrict__ hs,
                                                         const float* __restrict__ dinv,
                                                         const float* __restrict__ b1,
                                                         const float* __restrict__ W2,
                                                         __half* __restrict__ gs) {
    __shared__ float sW[HID_C * OUT_C];                 // 8 KB, [k][c] row-major
    __shared__ float sh[32 * 68];                       // 32 nodes x 64ch, stride 68 (bank-spread)
    for (int i = threadIdx.x; i < HID_C * OUT_C; i += 256) sW[i] = W2[i];
    const int ln = threadIdx.x >> 3;                    // node slot 0..31
    const int cl = threadIdx.x & 7;                     // lane in node: channels 8cl..8cl+7
    const int node = blockIdx.x * 32 + ln;              // grid 3125 exact
    const int beg = row_ptr[node], end = row_ptr[node + 1];
    const char* hsb = (const char*)hs;
    const int lo = cl * 16;                             // byte offset within 128-B row
    float one = 1.0f;
    float a0 = 0.f, a1 = 0.f, a2 = 0.f, a3 = 0.f, a4 = 0.f, a5 = 0.f, a6 = 0.f, a7 = 0.f;
    {
        uint4 sv = *(const uint4*)(hsb + node * 128 + lo);   // self loop
        ACC8(sv, one);
    }
    int j = beg;
    for (; j + 8 <= end; j += 8) {                      // 8 independent gathers in flight
        int i0 = col[j],     i1 = col[j + 1], i2 = col[j + 2], i3 = col[j + 3];
        int i4 = col[j + 4], i5 = col[j + 5], i6 = col[j + 6], i7 = col[j + 7];
        uint4 v0 = *(const uint4*)(hsb + i0 * 128 + lo);
        uint4 v1 = *(const uint4*)(hsb + i1 * 128 + lo);
        uint4 v2 = *(const uint4*)(hsb + i2 * 128 + lo);
        uint4 v3 = *(const uint4*)(hsb + i3 * 128 + lo);
        uint4 v4 = *(const uint4*)(hsb + i4 * 128 + lo);
        uint4 v5 = *(const uint4*)(hsb + i5 * 128 + lo);
        uint4 v6 = *(const uint4*)(hsb + i6 * 128 + lo);
        uint4 v7 = *(const uint4*)(hsb + i7 * 128 + lo);
        ACC8(v0, one); ACC8(v1, one); ACC8(v2, one); ACC8(v3, one);
        ACC8(v4, one); ACC8(v5, one); ACC8(v6, one); ACC8(v7, one);
    }
    if (j < end) {                                      // predicated tail, 8 deep
        const int e1 = end - 1;
#pragma unroll
        for (int k = 0; k < 8; ++k) {
            int jj = j + k;
            int s = col[min(jj, e1)];
            float wt = (jj < end) ? 1.0f : 0.0f;
            uint4 v = *(const uint4*)(hsb + s * 128 + lo);
            ACC8(v, wt);
        }
    }
    const float dv = dinv[node];
    const float4* b4 = (const float4*)b1;
    float4 bb0 = b4[2 * cl], bb1 = b4[2 * cl + 1];
    float4 h0, h1;
    h0.x = fmaxf(fmaf(dv, a0, bb0.x), 0.f);
    h0.y = fmaxf(fmaf(dv, a1, bb0.y), 0.f);
    h0.z = fmaxf(fmaf(dv, a2, bb0.z), 0.f);
    h0.w = fmaxf(fmaf(dv, a3, bb0.w), 0.f);
    h1.x = fmaxf(fmaf(dv, a4, bb1.x), 0.f);
    h1.y = fmaxf(fmaf(dv, a5, bb1.y), 0.f);
    h1.z = fmaxf(fmaf(dv, a6, bb1.z), 0.f);
    h1.w = fmaxf(fmaf(dv, a7, bb1.w), 0.f);
    *(float4*)&sh[ln * 68 + 8 * cl] = h0;               // h2 row, fp32 in LDS
    *(float4*)&sh[ln * 68 + 8 * cl + 4] = h1;
    __syncthreads();                                    // also covers sW load
    // gs[node][oc..oc+3] = dv * sum_k h2[k] * W2[k][oc..oc+3]
    float g0 = 0.f, g1 = 0.f, g2 = 0.f, g3 = 0.f;
    const int oc = 4 * cl;
#pragma unroll
    for (int k4 = 0; k4 < HID_C / 4; ++k4) {
        float4 hv = *(const float4*)&sh[ln * 68 + 4 * k4];   // bank 4(ln+k4)%32: conflict-free
#pragma unroll
        for (int q = 0; q < 4; ++q) {
            float hq = (q == 0) ? hv.x : (q == 1) ? hv.y : (q == 2) ? hv.z : hv.w;
            float4 wv = *(const float4*)&sW[(4 * k4 + q) * OUT_C + oc];
            g0 = fmaf(hq, wv.x, g0);
            g1 = fmaf(hq, wv.y, g1);
            g2 = fmaf(hq, wv.z, g2);
            g3 = fmaf(hq, wv.w, g3);
        }
    }
    union { uint2 u; __half2 h[2]; } go;
    go.h[0] = __floats2half2_rn(g0 * dv, g1 * dv);
    go.h[1] = __floats2half2_rn(g2 * dv, g3 * dv);
    *(uint2*)(gs + (size_t)node * OUT_C + oc) = go.u;   // 8 B x 8 lanes = 64 B/node
}

// ---- layer-2 aggregate: 8 nodes/wave, 8 lanes/node SPLIT INTO TWO 4-LANE HALVES:
//      low half (sl 0-3) takes even edges, high half (sl 4-7) odd edges; each lane
//      loads uint4 = 16 B = quarter of the 64-B row. One wave instruction now
//      gathers 16 edges x 64 B = 1 KB (2x round-7 width) with UNCHANGED
//      divergence (still 8 nodes/wave). Halves combine via 8 shfl_xor(.,4) adds. ----
__global__ __launch_bounds__(256) void agg2_kernel(const int* __restrict__ row_ptr,
                                                   const int* __restrict__ col,
                                                   const __half* __restrict__ gsr,
                                                   const float* __restrict__ dinv,
                                                   const float* __restrict__ b2,
                                                   float* __restrict__ out) {
    const int ln = threadIdx.x >> 3;                    // node slot 0..31
    const int sl = threadIdx.x & 7;                     // sub-lane in node group
    const int q4 = sl & 3;                              // quarter-row: channels 8*q4..+7
    const int par = sl >> 2;                            // 0 = even edges, 1 = odd edges
    const int node = blockIdx.x * 32 + ln;              // grid 3125 exact
    const int beg = row_ptr[node], end = row_ptr[node + 1];
    const char* gb = (const char*)gsr;
    const int lo = q4 * 16;                             // byte offset within 64-B row
    float one = 1.0f;
    float a0 = 0.f, a1 = 0.f, a2 = 0.f, a3 = 0.f, a4 = 0.f, a5 = 0.f, a6 = 0.f, a7 = 0.f;
    {
        uint4 sv = *(const uint4*)(gb + node * 64 + lo);     // self loop
        float wt = par ? 0.0f : 1.0f;                   // only even half adds self
        ACC8(sv, wt);
    }
    int jb = beg;
    for (; jb + 16 <= end; jb += 16) {                  // 16 edges/iter, 8 gathers/lane
        int i0 = col[jb + 0 + par], i1 = col[jb + 2 + par];
        int i2 = col[jb + 4 + par], i3 = col[jb + 6 + par];
        int i4 = col[jb + 8 + par], i5 = col[jb + 10 + par];
        int i6 = col[jb + 12 + par], i7 = col[jb + 14 + par];
        uint4 v0 = *(const uint4*)(gb + i0 * 64 + lo);
        uint4 v1 = *(const uint4*)(gb + i1 * 64 + lo);
        uint4 v2 = *(const uint4*)(gb + i2 * 64 + lo);
        uint4 v3 = *(const uint4*)(gb + i3 * 64 + lo);
        uint4 v4 = *(const uint4*)(gb + i4 * 64 + lo);
        uint4 v5 = *(const uint4*)(gb + i5 * 64 + lo);
        uint4 v6 = *(const uint4*)(gb + i6 * 64 + lo);
        uint4 v7 = *(const uint4*)(gb + i7 * 64 + lo);
        ACC8(v0, one); ACC8(v1, one); ACC8(v2, one); ACC8(v3, one);
        ACC8(v4, one); ACC8(v5, one); ACC8(v6, one); ACC8(v7, one);
    }
    if (jb < end) {                                     // predicated tail covers <16 edges
        const int e1 = end - 1;
#pragma unroll
        for (int k = 0; k < 8; ++k) {
            int jj = jb + 2 * k + par;
            int s = col[min(jj, e1)];
            float wt = (jj < end) ? 1.0f : 0.0f;
            uint4 v = *(const uint4*)(gb + s * 64 + lo);
            ACC8(v, wt);
        }
    }
    // combine even/odd halves (partner lane has SAME channels, other edge subset)
    a0 += __shfl_xor(a0, 4); a1 += __shfl_xor(a1, 4);
    a2 += __shfl_xor(a2, 4); a3 += __shfl_xor(a3, 4);
    a4 += __shfl_xor(a4, 4); a5 += __shfl_xor(a5, 4);
    a6 += __shfl_xor(a6, 4); a7 += __shfl_xor(a7, 4);
    if (par == 0) {                                     // low half writes 32 B each
        const float dv = dinv[node];
        const float4* b4 = (const float4*)b2;
        float4 bb0 = b4[2 * q4], bb1 = b4[2 * q4 + 1];
        float4 o0, o1;
        o0.x = fmaf(dv, a0, bb0.x);
        o0.y = fmaf(dv, a1, bb0.y);
        o0.z = fmaf(dv, a2, bb0.z);
        o0.w = fmaf(dv, a3, bb0.w);
        o1.x = fmaf(dv, a4, bb1.x);
        o1.y = fmaf(dv, a5, bb1.y);
        o1.z = fmaf(dv, a6, bb1.z);
        o1.w = fmaf(dv, a7, bb1.w);
        float* op = out + (size_t)node * OUT_C + 8 * q4;
        *(float4*)op = o0;                              // 4 lanes x 32 B = 128 B/node
        *(float4*)(op + 4) = o1;
    }
}

extern "C" void kernel_launch(void* const* d_in, const int* in_sizes, int n_in,
                              void* d_out, int out_size, void* d_ws, size_t ws_size,
                              hipStream_t stream) {
    const float* x  = (const float*)d_in[0];   // [N,128]
    const int*   ei = (const int*)d_in[1];     // [2,E]
    const float* W1 = (const float*)d_in[2];   // [128,64]
    const float* b1 = (const float*)d_in[3];   // [64]
    const float* W2 = (const float*)d_in[4];   // [64,32]
    const float* b2 = (const float*)d_in[5];   // [32]
    float* out = (float*)d_out;                // [N,32]

    const int* srcv = ei;
    const int* dstv = ei + E_EDGES;

    // workspace layout (~33 MB)
    float* dinv  = (float*)d_ws;                           // N floats
    __half* hs   = (__half*)(dinv + N_NODES);              // N*64 halves (layer-1 features)
    __half* gs   = hs + (size_t)N_NODES * HID_C;           // N*32 halves (fused agg1+gemm2 out;
                                                           //  must NOT alias hs — read concurrently)
    int* hist      = (int*)(gs + (size_t)N_NODES * HID_C); // NBUCK*NCHUNK (100k)
    int* bsums     = hist + SCAN_N;                        // NBUCK bucket base offsets
    int* row_ptr   = bsums + SCAN_NB;                      // N+1
    unsigned* pairs = (unsigned*)(row_ptr + N_NODES + 1);  // E (pairs -> sorted src = col)
    int* col = (int*)pairs;

    // CSR build: chunk-privatized counting sort (bucket-ordered scan, round-7 form)
    chunk_hist_kernel<<<NCHUNK, 1024, 0, stream>>>(dstv, hist);
    scan1_kernel<<<SCAN_NB, 256, 0, stream>>>(hist, bsums);
    scan2_kernel<<<1, 1024, 0, stream>>>(bsums);
    chunk_fill_kernel<<<NCHUNK, 1024, 0, stream>>>(srcv, dstv, hist, bsums, pairs);
    bucket_sort_kernel<<<NBUCK, 256, 0, stream>>>(bsums, pairs, row_ptr, dinv);

    // layer 1 (+ fused layer-2 GEMM)
    gemm1_kernel<<<(N_NODES + 127) / 128, 256, 0, stream>>>(x, W1, dinv, hs);
    agg1_gemm2_kernel<<<N_NODES / 32, 256, 0, stream>>>(row_ptr, col, hs, dinv, b1, W2, gs);

    // layer 2 aggregate
    agg2_kernel<<<N_NODES / 32, 256, 0, stream>>>(row_ptr, col, gs, dinv, b2, out);
}

// Round 11
// 200.218 us; speedup vs baseline: 1.0218x; 1.0004x over previous
//
#include <hip/hip_runtime.h>
#include <hip/hip_fp16.h>

#define N_NODES 100000
#define E_EDGES 1600000
#define IN_C 128
#define HID_C 64
#define OUT_C 32
#define BNODES 256                                  // nodes per bucket (dst>>8)
#define NBUCK ((N_NODES + BNODES - 1) / BNODES)     // 391
#define MAXB 4608                                   // bucket cap (mean 4092, sd~64 -> +8 sigma)
#define NCHUNK 256                                  // edge chunks (privatized sort)
#define CHUNK_E (E_EDGES / NCHUNK)                  // 6250
#define SCAN_N (NBUCK * NCHUNK)                     // 100096 counts
#define SCAN_NB (SCAN_N / 256)                      // 391 blocks (bsums[i] pairs with hist row i)
#define NT 8                                        // src tiles (12.8MB hs / 8 = 1.6MB/tile)
#define TILE_DIV 12500                              // src / 12500 -> tile 0..7

// v_fma_mix_f32: acc(f32) += cvt_f32(f16 half of u) * wt(f32). One VALU per channel-value
// (vs cvt+add = 2), fp32 accumulation preserved exactly.
#define FMX_LO(acc, u, wt) asm("v_fma_mix_f32 %0, %1, %2, %0 op_sel:[0,0,0] op_sel_hi:[1,0,0]" \
                               : "+v"(acc) : "v"(u), "v"(wt))
#define FMX_HI(acc, u, wt) asm("v_fma_mix_f32 %0, %1, %2, %0 op_sel:[1,0,0] op_sel_hi:[1,0,0]" \
                               : "+v"(acc) : "v"(u), "v"(wt))

// NOTE: macro param must NOT be named 'w'/'x'/'y'/'z' — it would substitute into the
// vector member access (v).w (round-2 compile failure).
#define ACC8(v, wt) do { \
        FMX_LO(a0, (v).x, wt); FMX_HI(a1, (v).x, wt); \
        FMX_LO(a2, (v).y, wt); FMX_HI(a3, (v).y, wt); \
        FMX_LO(a4, (v).z, wt); FMX_HI(a5, (v).z, wt); \
        FMX_LO(a6, (v).w, wt); FMX_HI(a7, (v).w, wt); } while (0)

// chunk<->block swizzle: consecutive chunks land on the same XCD (blockIdx%8 heuristic),
// so adjacent pairs-windows (shared 64B lines) merge in one L2 instead of ping-ponging.
__device__ __forceinline__ int chunk_of_block(int b) { return (b & 7) * (NCHUNK / 8) + (b >> 3); }

// ---- chunk histogram: block k histograms its 6250-edge slice in LDS (1024 thr) ----
__global__ __launch_bounds__(1024) void chunk_hist_kernel(const int* __restrict__ dst,
                                                          int* __restrict__ hist) {
    __shared__ int h[NBUCK];
    for (int i = threadIdx.x; i < NBUCK; i += 1024) h[i] = 0;
    __syncthreads();
    const int chunk = chunk_of_block(blockIdx.x);
    const int base = chunk * CHUNK_E;
    for (int j = threadIdx.x; j < CHUNK_E; j += 1024)
        atomicAdd(&h[dst[base + j] >> 8], 1);
    __syncthreads();
    for (int i = threadIdx.x; i < NBUCK; i += 1024)
        hist[i * NCHUNK + chunk] = h[i];
}

// ---- scan stage 1: per-256-block (= per-bucket-row) exclusive scan; row totals out ----
__global__ void scan1_kernel(int* __restrict__ data, int* __restrict__ bsums) {
    __shared__ int s[256];
    int i = blockIdx.x * 256 + threadIdx.x;
    int v = data[i];
    s[threadIdx.x] = v;
    __syncthreads();
    for (int off = 1; off < 256; off <<= 1) {
        int t = (threadIdx.x >= off) ? s[threadIdx.x - off] : 0;
        __syncthreads();
        s[threadIdx.x] += t;
        __syncthreads();
    }
    data[i] = s[threadIdx.x] - v;                   // exclusive within bucket row
    if (threadIdx.x == 255) bsums[blockIdx.x] = s[255];
}

// ---- scan stage 2: exclusive scan of the 391 block sums (single block, 1 pass) ----
__global__ __launch_bounds__(1024) void scan2_kernel(int* __restrict__ bsums) {
    __shared__ int s[1024];
    int i = threadIdx.x;
    int v = (i < SCAN_NB) ? bsums[i] : 0;
    s[i] = v;
    __syncthreads();
    for (int off = 1; off < 1024; off <<= 1) {
        int t = (i >= off) ? s[i - off] : 0;
        __syncthreads();
        s[i] += t;
        __syncthreads();
    }
    if (i < SCAN_NB) bsums[i] = s[i] - v;
}

// ---- chunk fill: block k scatters its slice into PRIVATE windows.
//      Global offset of (bucket i, chunk) = hist[i*256+chunk] + bsums[i]. ----
__global__ __launch_bounds__(1024) void chunk_fill_kernel(const int* __restrict__ src,
                                                          const int* __restrict__ dst,
                                                          const int* __restrict__ hist,
                                                          const int* __restrict__ bsums,
                                                          unsigned* __restrict__ pairs) {
    __shared__ int cur[NBUCK];
    const int chunk = chunk_of_block(blockIdx.x);
    for (int i = threadIdx.x; i < NBUCK; i += 1024)
        cur[i] = hist[i * NCHUNK + chunk] + bsums[i];
    __syncthreads();
    const int base = chunk * CHUNK_E;
    for (int j = threadIdx.x; j < CHUNK_E; j += 1024) {
        int d = dst[base + j];
        int pos = atomicAdd(&cur[d >> 8], 1);
        pairs[pos] = ((unsigned)src[base + j] << 8) | (unsigned)(d & 255);
    }
}

// ---- per-bucket counting sort -> node-level CSR, in place (LDS stage).
//      Sort key = (node, src/12500): neighbor lists come out src-tile-ordered. ----
__global__ __launch_bounds__(256) void bucket_sort_kernel(const int* __restrict__ bsums,
                                                          unsigned* __restrict__ pairs,
                                                          int* __restrict__ row_ptr,
                                                          float* __restrict__ dinv) {
    __shared__ unsigned sp[MAXB];
    __shared__ unsigned so[MAXB];
    __shared__ int cur[BNODES * NT];                // 2048 counters (node x tile)
    __shared__ int s256[BNODES];
    const int b = blockIdx.x;
    const int tid = threadIdx.x;
    const int beg = bsums[b];
    const int end = (b + 1 < NBUCK) ? bsums[b + 1] : E_EDGES;
    const int cnt = end - beg;
#pragma unroll
    for (int q = 0; q < NT; ++q) cur[tid * NT + q] = 0;
    __syncthreads();
    for (int j = tid; j < cnt; j += 256) {
        unsigned p = pairs[beg + j];
        sp[j] = p;
        atomicAdd(&cur[(p & 255) * NT + (p >> 8) / TILE_DIV], 1);
    }
    __syncthreads();
    int a[NT];
    int lsum = 0;
#pragma unroll
    for (int q = 0; q < NT; ++q) { a[q] = cur[tid * NT + q]; lsum += a[q]; }
    s256[tid] = lsum;
    __syncthreads();
    for (int off = 1; off < 256; off <<= 1) {       // inclusive scan over node totals
        int t = (tid >= off) ? s256[tid - off] : 0;
        __syncthreads();
        s256[tid] += t;
        __syncthreads();
    }
    int run = s256[tid] - lsum;                     // exclusive prefix for this node
    int node = b * BNODES + tid;
    if (node < N_NODES) {
        row_ptr[node] = beg + run;
        dinv[node] = rsqrtf((float)lsum + 1.0f);
    }
    if (tid == 0 && b == NBUCK - 1) row_ptr[N_NODES] = E_EDGES;
#pragma unroll
    for (int q = 0; q < NT; ++q) { cur[tid * NT + q] = run; run += a[q]; }
    __syncthreads();
    for (int j = tid; j < cnt; j += 256) {
        unsigned p = sp[j];
        int pos = atomicAdd(&cur[(p & 255) * NT + (p >> 8) / TILE_DIV], 1);
        so[pos] = p >> 8;                           // scatter stays in LDS
    }
    __syncthreads();
    for (int j = tid; j < cnt; j += 256)
        pairs[beg + j] = so[j];                     // coalesced writeback
}

// ---- hs(fp16) = dinv[row] * (x @ W1) : 4 rows x 8 cols per thread, 128 rows/block ----
__global__ __launch_bounds__(256) void gemm1_kernel(const float* __restrict__ x,
                                                    const float* __restrict__ W1,
                                                    const float* __restrict__ dinv,
                                                    __half* __restrict__ hs) {
    __shared__ float sW[IN_C * HID_C];
    for (int i = threadIdx.x; i < IN_C * HID_C; i += 256) sW[i] = W1[i];
    __syncthreads();
    const int cg = (threadIdx.x & 7) * 8;
    const int row0 = blockIdx.x * 128 + (threadIdx.x >> 3) * 4;
    float acc[4][8];
#pragma unroll
    for (int r = 0; r < 4; ++r)
#pragma unroll
        for (int c = 0; c < 8; ++c) acc[r][c] = 0.f;

    int rr[4];
#pragma unroll
    for (int r = 0; r < 4; ++r) rr[r] = min(row0 + r, N_NODES - 1);

    const float4* x4 = (const float4*)x;
#pragma unroll 2
    for (int k4 = 0; k4 < IN_C / 4; ++k4) {
        float4 xv[4];
#pragma unroll
        for (int r = 0; r < 4; ++r) xv[r] = x4[(size_t)rr[r] * (IN_C / 4) + k4];
        float xs[4][4];
#pragma unroll
        for (int r = 0; r < 4; ++r) {
            xs[r][0] = xv[r].x; xs[r][1] = xv[r].y; xs[r][2] = xv[r].z; xs[r][3] = xv[r].w;
        }
#pragma unroll
        for (int kk = 0; kk < 4; ++kk) {
            const float4* wp = (const float4*)(sW + (k4 * 4 + kk) * HID_C + cg);
            float4 w0 = wp[0], w1 = wp[1];
            float wv[8] = {w0.x, w0.y, w0.z, w0.w, w1.x, w1.y, w1.z, w1.w};
#pragma unroll
            for (int r = 0; r < 4; ++r)
#pragma unroll
                for (int c = 0; c < 8; ++c)
                    acc[r][c] = fmaf(xs[r][kk], wv[c], acc[r][c]);
        }
    }
#pragma unroll
    for (int r = 0; r < 4; ++r) {
        int row = row0 + r;
        if (row < N_NODES) {
            float dv = dinv[row];
            union { float4 f; __half2 h[4]; } u;
#pragma unroll
            for (int q = 0; q < 4; ++q)
                u.h[q] = __floats2half2_rn(acc[r][2 * q] * dv, acc[r][2 * q + 1] * dv);
            *(float4*)(hs + (size_t)row * HID_C + cg) = u.f;   // 16 B packed store
        }
    }
}

// ---- layer-1 aggregate FUSED with gemm2. 8 nodes/wave, 8 lanes/node, uint4 (16B =
//      8 fp16 channels) per lane. One gather instruction = 8 edges x 128B rows = 1KB.
//      (round-7 proven form) ----
__global__ __launch_bounds__(256) void agg1_gemm2_kernel(const int* __restrict__ row_ptr,
                                                         const int* __restrict__ col,
                                                         const __half* __restrict__ hs,
                                                         const float* __restrict__ dinv,
                                                         const float* __restrict__ b1,
                                                         const float* __restrict__ W2,
                                                         __half* __restrict__ gs) {
    __shared__ float sW[HID_C * OUT_C];                 // 8 KB, [k][c] row-major
    __shared__ float sh[32 * 68];                       // 32 nodes x 64ch, stride 68 (bank-spread)
    for (int i = threadIdx.x; i < HID_C * OUT_C; i += 256) sW[i] = W2[i];
    const int ln = threadIdx.x >> 3;                    // node slot 0..31
    const int cl = threadIdx.x & 7;                     // lane in node: channels 8cl..8cl+7
    const int node = blockIdx.x * 32 + ln;              // grid 3125 exact
    const int beg = row_ptr[node], end = row_ptr[node + 1];
    const char* hsb = (const char*)hs;
    const int lo = cl * 16;                             // byte offset within 128-B row
    float one = 1.0f;
    float a0 = 0.f, a1 = 0.f, a2 = 0.f, a3 = 0.f, a4 = 0.f, a5 = 0.f, a6 = 0.f, a7 = 0.f;
    {
        uint4 sv = *(const uint4*)(hsb + node * 128 + lo);   // self loop
        ACC8(sv, one);
    }
    int j = beg;
    for (; j + 8 <= end; j += 8) {                      // 8 independent gathers in flight
        int i0 = col[j],     i1 = col[j + 1], i2 = col[j + 2], i3 = col[j + 3];
        int i4 = col[j + 4], i5 = col[j + 5], i6 = col[j + 6], i7 = col[j + 7];
        uint4 v0 = *(const uint4*)(hsb + i0 * 128 + lo);
        uint4 v1 = *(const uint4*)(hsb + i1 * 128 + lo);
        uint4 v2 = *(const uint4*)(hsb + i2 * 128 + lo);
        uint4 v3 = *(const uint4*)(hsb + i3 * 128 + lo);
        uint4 v4 = *(const uint4*)(hsb + i4 * 128 + lo);
        uint4 v5 = *(const uint4*)(hsb + i5 * 128 + lo);
        uint4 v6 = *(const uint4*)(hsb + i6 * 128 + lo);
        uint4 v7 = *(const uint4*)(hsb + i7 * 128 + lo);
        ACC8(v0, one); ACC8(v1, one); ACC8(v2, one); ACC8(v3, one);
        ACC8(v4, one); ACC8(v5, one); ACC8(v6, one); ACC8(v7, one);
    }
    if (j < end) {                                      // predicated tail, 8 deep
        const int e1 = end - 1;
#pragma unroll
        for (int k = 0; k < 8; ++k) {
            int jj = j + k;
            int s = col[min(jj, e1)];
            float wt = (jj < end) ? 1.0f : 0.0f;
            uint4 v = *(const uint4*)(hsb + s * 128 + lo);
            ACC8(v, wt);
        }
    }
    const float dv = dinv[node];
    const float4* b4 = (const float4*)b1;
    float4 bb0 = b4[2 * cl], bb1 = b4[2 * cl + 1];
    float4 h0, h1;
    h0.x = fmaxf(fmaf(dv, a0, bb0.x), 0.f);
    h0.y = fmaxf(fmaf(dv, a1, bb0.y), 0.f);
    h0.z = fmaxf(fmaf(dv, a2, bb0.z), 0.f);
    h0.w = fmaxf(fmaf(dv, a3, bb0.w), 0.f);
    h1.x = fmaxf(fmaf(dv, a4, bb1.x), 0.f);
    h1.y = fmaxf(fmaf(dv, a5, bb1.y), 0.f);
    h1.z = fmaxf(fmaf(dv, a6, bb1.z), 0.f);
    h1.w = fmaxf(fmaf(dv, a7, bb1.w), 0.f);
    *(float4*)&sh[ln * 68 + 8 * cl] = h0;               // h2 row, fp32 in LDS
    *(float4*)&sh[ln * 68 + 8 * cl + 4] = h1;
    __syncthreads();                                    // also covers sW load
    // gs[node][oc..oc+3] = dv * sum_k h2[k] * W2[k][oc..oc+3]
    float g0 = 0.f, g1 = 0.f, g2 = 0.f, g3 = 0.f;
    const int oc = 4 * cl;
#pragma unroll
    for (int k4 = 0; k4 < HID_C / 4; ++k4) {
        float4 hv = *(const float4*)&sh[ln * 68 + 4 * k4];   // bank 4(ln+k4)%32: conflict-free
#pragma unroll
        for (int q = 0; q < 4; ++q) {
            float hq = (q == 0) ? hv.x : (q == 1) ? hv.y : (q == 2) ? hv.z : hv.w;
            float4 wv = *(const float4*)&sW[(4 * k4 + q) * OUT_C + oc];
            g0 = fmaf(hq, wv.x, g0);
            g1 = fmaf(hq, wv.y, g1);
            g2 = fmaf(hq, wv.z, g2);
            g3 = fmaf(hq, wv.w, g3);
        }
    }
    union { uint2 u; __half2 h[2]; } go;
    go.h[0] = __floats2half2_rn(g0 * dv, g1 * dv);
    go.h[1] = __floats2half2_rn(g2 * dv, g3 * dv);
    *(uint2*)(gs + (size_t)node * OUT_C + oc) = go.u;   // 8 B x 8 lanes = 64 B/node
}

// ---- layer-2 aggregate: 8 nodes/wave, 8 lanes/node SPLIT INTO TWO 4-LANE HALVES:
//      low half (sl 0-3) takes even edges, high half (sl 4-7) odd edges; each lane
//      loads uint4 = 16 B = quarter of the 64-B row. One wave instruction now
//      gathers 16 edges x 64 B = 1 KB with UNCHANGED divergence (8 nodes/wave).
//      Halves combine via 8 shfl_xor(.,4) adds. (round-9 proven, -2.1 us) ----
__global__ __launch_bounds__(256) void agg2_kernel(const int* __restrict__ row_ptr,
                                                   const int* __restrict__ col,
                                                   const __half* __restrict__ gsr,
                                                   const float* __restrict__ dinv,
                                                   const float* __restrict__ b2,
                                                   float* __restrict__ out) {
    const int ln = threadIdx.x >> 3;                    // node slot 0..31
    const int sl = threadIdx.x & 7;                     // sub-lane in node group
    const int q4 = sl & 3;                              // quarter-row: channels 8*q4..+7
    const int par = sl >> 2;                            // 0 = even edges, 1 = odd edges
    const int node = blockIdx.x * 32 + ln;              // grid 3125 exact
    const int beg = row_ptr[node], end = row_ptr[node + 1];
    const char* gb = (const char*)gsr;
    const int lo = q4 * 16;                             // byte offset within 64-B row
    float one = 1.0f;
    float a0 = 0.f, a1 = 0.f, a2 = 0.f, a3 = 0.f, a4 = 0.f, a5 = 0.f, a6 = 0.f, a7 = 0.f;
    {
        uint4 sv = *(const uint4*)(gb + node * 64 + lo);     // self loop
        float wt = par ? 0.0f : 1.0f;                   // only even half adds self
        ACC8(sv, wt);
    }
    int jb = beg;
    for (; jb + 16 <= end; jb += 16) {                  // 16 edges/iter, 8 gathers/lane
        int i0 = col[jb + 0 + par], i1 = col[jb + 2 + par];
        int i2 = col[jb + 4 + par], i3 = col[jb + 6 + par];
        int i4 = col[jb + 8 + par], i5 = col[jb + 10 + par];
        int i6 = col[jb + 12 + par], i7 = col[jb + 14 + par];
        uint4 v0 = *(const uint4*)(gb + i0 * 64 + lo);
        uint4 v1 = *(const uint4*)(gb + i1 * 64 + lo);
        uint4 v2 = *(const uint4*)(gb + i2 * 64 + lo);
        uint4 v3 = *(const uint4*)(gb + i3 * 64 + lo);
        uint4 v4 = *(const uint4*)(gb + i4 * 64 + lo);
        uint4 v5 = *(const uint4*)(gb + i5 * 64 + lo);
        uint4 v6 = *(const uint4*)(gb + i6 * 64 + lo);
        uint4 v7 = *(const uint4*)(gb + i7 * 64 + lo);
        ACC8(v0, one); ACC8(v1, one); ACC8(v2, one); ACC8(v3, one);
        ACC8(v4, one); ACC8(v5, one); ACC8(v6, one); ACC8(v7, one);
    }
    if (jb < end) {                                     // predicated tail covers <16 edges
        const int e1 = end - 1;
#pragma unroll
        for (int k = 0; k < 8; ++k) {
            int jj = jb + 2 * k + par;
            int s = col[min(jj, e1)];
            float wt = (jj < end) ? 1.0f : 0.0f;
            uint4 v = *(const uint4*)(gb + s * 64 + lo);
            ACC8(v, wt);
        }
    }
    // combine even/odd halves (partner lane has SAME channels, other edge subset)
    a0 += __shfl_xor(a0, 4); a1 += __shfl_xor(a1, 4);
    a2 += __shfl_xor(a2, 4); a3 += __shfl_xor(a3, 4);
    a4 += __shfl_xor(a4, 4); a5 += __shfl_xor(a5, 4);
    a6 += __shfl_xor(a6, 4); a7 += __shfl_xor(a7, 4);
    if (par == 0) {                                     // low half writes 32 B each
        const float dv = dinv[node];
        const float4* b4 = (const float4*)b2;
        float4 bb0 = b4[2 * q4], bb1 = b4[2 * q4 + 1];
        float4 o0, o1;
        o0.x = fmaf(dv, a0, bb0.x);
        o0.y = fmaf(dv, a1, bb0.y);
        o0.z = fmaf(dv, a2, bb0.z);
        o0.w = fmaf(dv, a3, bb0.w);
        o1.x = fmaf(dv, a4, bb1.x);
        o1.y = fmaf(dv, a5, bb1.y);
        o1.z = fmaf(dv, a6, bb1.z);
        o1.w = fmaf(dv, a7, bb1.w);
        float* op = out + (size_t)node * OUT_C + 8 * q4;
        *(float4*)op = o0;                              // 4 lanes x 32 B = 128 B/node
        *(float4*)(op + 4) = o1;
    }
}

extern "C" void kernel_launch(void* const* d_in, const int* in_sizes, int n_in,
                              void* d_out, int out_size, void* d_ws, size_t ws_size,
                              hipStream_t stream) {
    const float* x  = (const float*)d_in[0];   // [N,128]
    const int*   ei = (const int*)d_in[1];     // [2,E]
    const float* W1 = (const float*)d_in[2];   // [128,64]
    const float* b1 = (const float*)d_in[3];   // [64]
    const float* W2 = (const float*)d_in[4];   // [64,32]
    const float* b2 = (const float*)d_in[5];   // [32]
    float* out = (float*)d_out;                // [N,32]

    const int* srcv = ei;
    const int* dstv = ei + E_EDGES;

    // workspace layout (~33 MB)
    float* dinv  = (float*)d_ws;                           // N floats
    __half* hs   = (__half*)(dinv + N_NODES);              // N*64 halves (layer-1 features)
    __half* gs   = hs + (size_t)N_NODES * HID_C;           // N*32 halves (fused agg1+gemm2 out;
                                                           //  must NOT alias hs — read concurrently)
    int* hist      = (int*)(gs + (size_t)N_NODES * HID_C); // NBUCK*NCHUNK (100k)
    int* bsums     = hist + SCAN_N;                        // NBUCK bucket base offsets
    int* row_ptr   = bsums + SCAN_NB;                      // N+1
    unsigned* pairs = (unsigned*)(row_ptr + N_NODES + 1);  // E (pairs -> sorted src = col)
    int* col = (int*)pairs;

    // CSR build: chunk-privatized counting sort (bucket-ordered scan, round-7 form)
    chunk_hist_kernel<<<NCHUNK, 1024, 0, stream>>>(dstv, hist);
    scan1_kernel<<<SCAN_NB, 256, 0, stream>>>(hist, bsums);
    scan2_kernel<<<1, 1024, 0, stream>>>(bsums);
    chunk_fill_kernel<<<NCHUNK, 1024, 0, stream>>>(srcv, dstv, hist, bsums, pairs);
    bucket_sort_kernel<<<NBUCK, 256, 0, stream>>>(bsums, pairs, row_ptr, dinv);

    // layer 1 (+ fused layer-2 GEMM)
    gemm1_kernel<<<(N_NODES + 127) / 128, 256, 0, stream>>>(x, W1, dinv, hs);
    agg1_gemm2_kernel<<<N_NODES / 32, 256, 0, stream>>>(row_ptr, col, hs, dinv, b1, W2, gs);

    // layer 2 aggregate
    agg2_kernel<<<N_NODES / 32, 256, 0, stream>>>(row_ptr, col, gs, dinv, b2, out);
}